// Round 1
// baseline (141.599 us; speedup 1.0000x reference)
//
#include <hip/hip_runtime.h>

#define NLAYER 255          // layers l = 1..255, layer_id k = l-1
#define SEQ    256          // cumsum length
#define TOTJ   32640        // sum_{l=1}^{255} (256-l)
#define CHUNKS 8
#define CHUNK_J (TOTJ / CHUNKS)   // 4080 (multiple of 4)
#define CHUNK_F4 (CHUNK_J / 4)    // 1020
#define THREADS 256

// ---------------------------------------------------------------------------
// Single fused kernel. grid = (CHUNKS, B). Block handles one (row, j-chunk).
//  - LDS inclusive scan of d row -> c[256] (c[0]=0)
//  - w[k] = mask^2.5 / (count_k * 255 * B)  in LDS (full scale folded in)
//  - stream hvec chunk with float4; decode (layer k, lo) analytically:
//      start(k) = (511k - k^2)/2 ;  261121 - 8j = (511-2k)^2 at boundaries
//      -> k = floor((511 - sqrt(261121 - 8j))/2), one int correction step,
//      then incremental advance across the 4 elements of the float4.
//  - per-block partial -> atomicAdd(out).  NO workspace, NO table, NO
//    separate reduce kernel.
// ---------------------------------------------------------------------------
__global__ __launch_bounds__(THREADS) void main_kernel(
        const float* __restrict__ d1layer,        // B x 255
        const float* __restrict__ hvec,           // B x 32640
        const float* __restrict__ mask,           // B x 255
        float* __restrict__ out,                  // scalar (pre-zeroed)
        float scale)                              // 1/(255*B)
{
    __shared__ float c[SEQ];
    __shared__ float w[NLAYER];
    __shared__ float red[THREADS / 64];

    const int b     = blockIdx.y;
    const int chunk = blockIdx.x;
    const int t     = threadIdx.x;

    // stage d (shifted by 1) and fully-scaled w
    c[t] = (t > 0) ? d1layer[b * NLAYER + (t - 1)] : 0.0f;
    if (t < NLAYER) {
        float mk = mask[b * NLAYER + t];
        // mask^2.5 = mk*mk*sqrt(mk); fold /count_k, /255, /B  (count = 255-k)
        w[t] = mk * mk * sqrtf(mk) * scale / (float)(NLAYER - t);
    }
    __syncthreads();

    // Hillis-Steele inclusive scan over 256 entries -> c[i] = sum d[0..i-1]
    #pragma unroll
    for (int off = 1; off < SEQ; off <<= 1) {
        float v   = c[t];
        float add = (t >= off) ? c[t - off] : 0.0f;
        __syncthreads();
        c[t] = v + add;
        __syncthreads();
    }

    const float4* hv4 =
        (const float4*)(hvec + (size_t)b * TOTJ + (size_t)chunk * CHUNK_J);
    const int jbase = chunk * CHUNK_J;

    float acc = 0.0f;
    for (int f4 = t; f4 < CHUNK_F4; f4 += THREADS) {
        float4 h = hv4[f4];
        int j = jbase + f4 * 4;

        // analytic decode of (k, lo) for element 0 of this float4
        float s = sqrtf((float)(261121 - 8 * j));
        int k  = (int)((511.0f - s) * 0.5f);
        int sk = (511 * k - k * k) >> 1;        // start(k), exact int
        int sk1 = sk + (NLAYER - k);            // start(k+1)
        if (sk1 <= j) { k++; sk = sk1; }
        if (sk > j)   { sk -= (NLAYER + 1 - k); k--; }  // start(k-1)=sk-(256-k)
        int lo = j - sk;

        float hh[4] = {h.x, h.y, h.z, h.w};
        #pragma unroll
        for (int e = 0; e < 4; ++e) {
            float dv = (c[lo + k + 1] - c[lo]) - hh[e];
            acc = fmaf(dv * dv, w[k], acc);
            // advance to next flat index (layer sizes >= 1 so single-step)
            int nxt = (lo + 1 == NLAYER - k) ? 1 : 0;
            lo = nxt ? 0 : (lo + 1);
            k += nxt;
        }
    }

    // wave (64-lane) shuffle reduce, then cross-wave via LDS
    #pragma unroll
    for (int off = 32; off > 0; off >>= 1)
        acc += __shfl_down(acc, off, 64);
    int lane = t & 63, wid = t >> 6;
    if (lane == 0) red[wid] = acc;
    __syncthreads();
    if (t == 0) {
        float s2 = 0.0f;
        #pragma unroll
        for (int i = 0; i < THREADS / 64; ++i) s2 += red[i];
        atomicAdd(out, s2);   // device-scope float atomic, one per block
    }
}

// ---------------------------------------------------------------------------
extern "C" void kernel_launch(void* const* d_in, const int* in_sizes, int n_in,
                              void* d_out, int out_size, void* d_ws, size_t ws_size,
                              hipStream_t stream) {
    const float* d1layer = (const float*)d_in[0];   // B x 1 x 255
    const float* hvec    = (const float*)d_in[1];   // B x 32640
    const float* mask    = (const float*)d_in[2];   // B x 255
    float* out = (float*)d_out;

    const int B = in_sizes[2] / NLAYER;             // 512

    // zero the scalar accumulator (graph-capturable memset node)
    hipMemsetAsync(out, 0, sizeof(float), stream);

    const float scale = 1.0f / ((float)NLAYER * (float)B);
    dim3 grid(CHUNKS, B);
    main_kernel<<<grid, THREADS, 0, stream>>>(d1layer, hvec, mask, out, scale);
}